// Round 1
// baseline (940.205 us; speedup 1.0000x reference)
//
#include <hip/hip_runtime.h>
#include <stdint.h>

// Problem constants (EdgeEncoder_28071906247258)
#define BB 4
#define NN 100000
#define DD 128
#define EE 262144   // 2^18 edges per batch
#define HH 128
#define OO 128

typedef __attribute__((ext_vector_type(4))) float f32x4;
typedef __attribute__((ext_vector_type(8))) __bf16 bf16x8;
typedef __attribute__((ext_vector_type(8))) unsigned short u16x8;

static __device__ __forceinline__ unsigned short f2bf(float f) {
    union { float f; unsigned u; } v; v.f = f;
    return (unsigned short)((v.u + 0x7fffu + ((v.u >> 16) & 1u)) >> 16);  // RNE
}

// ---------------------------------------------------------------------------
// Prep: swizzle W1 rows 0..255 (fp32 [257][128]) into bf16 B-fragment order:
//   frag(kt,nt): lane holds W[k = kt*32 + (lane>>4)*8 + j][n = nt*16 + (lane&15)]
//   flat ushort index = ((kt*8+nt)*64 + lane)*8 + j
// ---------------------------------------------------------------------------
__global__ __launch_bounds__(256) void prep_w1(const float* __restrict__ W1,
                                               unsigned short* __restrict__ w1f) {
    int t = blockIdx.x * 256 + threadIdx.x;          // grid exact: 128*256 = 32768
    int k = t >> 7, n = t & 127;
    int f = ((((k >> 5) * 8 + (n >> 4)) * 64) + ((k >> 3) & 3) * 16 + (n & 15)) * 8 + (k & 7);
    w1f[f] = f2bf(W1[t]);
}

__global__ __launch_bounds__(256) void prep_w2(const float* __restrict__ W2,
                                               unsigned short* __restrict__ w2f) {
    int t = blockIdx.x * 256 + threadIdx.x;          // grid exact: 64*256 = 16384
    int k = t >> 7, n = t & 127;
    int f = ((((k >> 5) * 8 + (n >> 4)) * 64) + ((k >> 3) & 3) * 16 + (n & 15)) * 8 + (k & 7);
    w2f[f] = f2bf(W2[t]);
}

// node_emb fp32 -> bf16 (same RNE conversion the hot loop used to do per-gather)
__global__ __launch_bounds__(256) void prep_node(const float* __restrict__ ne,
                                                 unsigned short* __restrict__ nb) {
    size_t t = (size_t)blockIdx.x * 256 + threadIdx.x;   // grid exact: 25000*256 -> 6.4M
    const f32x4* s = (const f32x4*)ne + (t << 1);
    f32x4 a = s[0], b = s[1];
    u16x8 o;
    o[0] = f2bf(a[0]); o[1] = f2bf(a[1]); o[2] = f2bf(a[2]); o[3] = f2bf(a[3]);
    o[4] = f2bf(b[0]); o[5] = f2bf(b[1]); o[6] = f2bf(b[2]); o[7] = f2bf(b[3]);
    *((u16x8*)nb + t) = o;
}

// ---------------------------------------------------------------------------
// Fused edge MLP. Block = 256 threads = 4 waves; each wave owns 32 edges
// (2 M-tiles of 16) -> acc[2][8] = 64 acc regs -> 4 waves/SIMD occupancy.
// All LDS is per-wave private -> NO __syncthreads (compiler handles wave-
// internal lgkmcnt ordering).
//   BF16N : gather pre-converted bf16 node rows (half traffic, no cvt)
//   W2LDS : last-resort tiny-workspace path (stage W2 frags in LDS)
// ---------------------------------------------------------------------------
template<bool BF16N, bool W2LDS>
__global__ __launch_bounds__(256, 4) void edge_mlp(
    const float* __restrict__ node_emb,
    const unsigned short* __restrict__ node_bf,
    const int* __restrict__ edge_index,
    const float* __restrict__ edge_sel,
    const float* __restrict__ W1,
    const float* __restrict__ b1,
    const float* __restrict__ W2,
    const float* __restrict__ b2,
    const unsigned short* __restrict__ w1f,
    const unsigned short* __restrict__ w2f,
    float* __restrict__ out)
{
    __shared__ unsigned short hst[4][2][16 * 136];   // per-wave, per-q h tiles (34816 B)
    __shared__ unsigned short w2s[W2LDS ? 16384 : 1];

    const int tid = threadIdx.x;

    if constexpr (W2LDS) {
        for (int s = tid; s < 16384; s += 256) {
            int k = s >> 7, n = s & 127;
            int f = ((((k >> 5) * 8 + (n >> 4)) * 64) + ((k >> 3) & 3) * 16 + (n & 15)) * 8 + (k & 7);
            w2s[f] = f2bf(W2[s]);
        }
        __syncthreads();
    }

    const int lane = tid & 63;
    const int wv = tid >> 6;
    const int nl = lane & 15;     // A-row lane / output-col lane
    const int quad = lane >> 4;   // 0..3

    // Per-lane epilogue constants: col = nt*16 + nl
    float b1v[8], w1cv[8];
#pragma unroll
    for (int nt = 0; nt < 8; ++nt) {
        b1v[nt] = b1[nt * 16 + nl];
        w1cv[nt] = W1[256 * 128 + nt * 16 + nl];  // W1 row 256 = sel weights
    }

    const int eb = blockIdx.x * 128 + wv * 32;  // global edge base of this wave
    const int bat = eb >> 18;                   // / EE
    const unsigned nbase = (unsigned)bat * (NN * DD);

    // Gather row offsets (element indices): lane's A-row edge = eb + mt*16 + nl
    unsigned ou[2], ov[2];
#pragma unroll
    for (int mt = 0; mt < 2; ++mt) {
        int e = eb + mt * 16 + nl;
        int iu = edge_index[(size_t)e * 2 + 0];
        int iv = edge_index[(size_t)e * 2 + 1];
        iu = min(max(iu, 0), NN - 1);
        iv = min(max(iv, 0), NN - 1);
        ou[mt] = nbase + (unsigned)iu * DD + quad * 8;
        ov[mt] = nbase + (unsigned)iv * DD + quad * 8;
    }

    // ---- Layer 1: acc[mt][nt] = X[32x256] * W1[256x128] ----
    f32x4 acc[2][8];
#pragma unroll
    for (int mt = 0; mt < 2; ++mt)
#pragma unroll
        for (int nt = 0; nt < 8; ++nt)
            acc[mt][nt] = f32x4{0.f, 0.f, 0.f, 0.f};

    const bf16x8* w1b = (const bf16x8*)w1f;
#pragma unroll
    for (int kt = 0; kt < 8; ++kt) {
        bf16x8 af[2];
#pragma unroll
        for (int mt = 0; mt < 2; ++mt) {
            unsigned o = ((kt < 4) ? ou[mt] : ov[mt]) + (kt & 3) * 32;
            if constexpr (BF16N) {
                af[mt] = *(const bf16x8*)(node_bf + o);
            } else {
                f32x4 x0 = *(const f32x4*)(node_emb + o);
                f32x4 x1 = *(const f32x4*)(node_emb + o + 4);
                bf16x8 a;
                a[0] = (__bf16)x0[0]; a[1] = (__bf16)x0[1];
                a[2] = (__bf16)x0[2]; a[3] = (__bf16)x0[3];
                a[4] = (__bf16)x1[0]; a[5] = (__bf16)x1[1];
                a[6] = (__bf16)x1[2]; a[7] = (__bf16)x1[3];
                af[mt] = a;
            }
        }
#pragma unroll
        for (int nt = 0; nt < 8; ++nt) {
            bf16x8 bf = w1b[(kt * 8 + nt) * 64 + lane];
            acc[0][nt] = __builtin_amdgcn_mfma_f32_16x16x32_bf16(af[0], bf, acc[0][nt], 0, 0, 0);
            acc[1][nt] = __builtin_amdgcn_mfma_f32_16x16x32_bf16(af[1], bf, acc[1][nt], 0, 0, 0);
        }
    }

    // ---- Epilogue 1 + per-wave LDS transpose (both q tiles, one wait point) ----
#pragma unroll
    for (int q = 0; q < 2; ++q) {
        float sel[4];
#pragma unroll
        for (int i = 0; i < 4; ++i)
            sel[i] = edge_sel[(size_t)(eb + q * 16 + quad * 4 + i)];
        unsigned short* hw = hst[wv][q];
#pragma unroll
        for (int nt = 0; nt < 8; ++nt) {
#pragma unroll
            for (int i = 0; i < 4; ++i) {
                float hv = acc[q][nt][i] + sel[i] * w1cv[nt] + b1v[nt];
                hv = fmaxf(hv, 0.f);
                hw[(quad * 4 + i) * 136 + nt * 16 + nl] = f2bf(hv);
            }
        }
    }

    // read back in A-operand layout: h[m=nl][k=kt2*32+quad*8+j]
    bf16x8 ha[2][4];
#pragma unroll
    for (int q = 0; q < 2; ++q)
#pragma unroll
        for (int kt2 = 0; kt2 < 4; ++kt2)
            ha[q][kt2] = *(const bf16x8*)(hst[wv][q] + nl * 136 + kt2 * 32 + quad * 8);

    // ---- Layer 2 ----
    f32x4 a2[2][8];
#pragma unroll
    for (int q = 0; q < 2; ++q)
#pragma unroll
        for (int nt = 0; nt < 8; ++nt)
            a2[q][nt] = f32x4{0.f, 0.f, 0.f, 0.f};

    const bf16x8* w2b = (const bf16x8*)(W2LDS ? (const unsigned short*)w2s : w2f);
#pragma unroll
    for (int kt2 = 0; kt2 < 4; ++kt2) {
#pragma unroll
        for (int nt = 0; nt < 8; ++nt) {
            bf16x8 bf = w2b[(kt2 * 8 + nt) * 64 + lane];
            a2[0][nt] = __builtin_amdgcn_mfma_f32_16x16x32_bf16(ha[0][kt2], bf, a2[0][nt], 0, 0, 0);
            a2[1][nt] = __builtin_amdgcn_mfma_f32_16x16x32_bf16(ha[1][kt2], bf, a2[1][nt], 0, 0, 0);
        }
    }

    // ---- Epilogue 2: relu(a2 + b2) -> out (non-temporal, stream past L2) ----
    float b2v[8];
#pragma unroll
    for (int nt = 0; nt < 8; ++nt)
        b2v[nt] = b2[nt * 16 + nl];

#pragma unroll
    for (int q = 0; q < 2; ++q) {
#pragma unroll
        for (int nt = 0; nt < 8; ++nt) {
#pragma unroll
            for (int i = 0; i < 4; ++i) {
                float o = a2[q][nt][i] + b2v[nt];
                o = fmaxf(o, 0.f);
                __builtin_nontemporal_store(
                    o, &out[(size_t)(eb + q * 16 + quad * 4 + i) * OO + nt * 16 + nl]);
            }
        }
    }
}

extern "C" void kernel_launch(void* const* d_in, const int* in_sizes, int n_in,
                              void* d_out, int out_size, void* d_ws, size_t ws_size,
                              hipStream_t stream) {
    const float* node_emb  = (const float*)d_in[0];
    const int*   edge_index= (const int*)d_in[1];
    const float* edge_sel  = (const float*)d_in[2];
    const float* W1        = (const float*)d_in[3];
    const float* b1        = (const float*)d_in[4];
    const float* W2        = (const float*)d_in[5];
    const float* b2        = (const float*)d_in[6];
    float* out             = (float*)d_out;

    unsigned short* w1f = (unsigned short*)d_ws;              // 64 KB
    const size_t NODE_BYTES = (size_t)BB * NN * DD * 2;       // 102,400,000 B
    const size_t NEED_B = 65536 + 32768;                      // w1f + w2f
    const size_t NEED_A = NEED_B + NODE_BYTES;

    prep_w1<<<dim3(128), dim3(256), 0, stream>>>(W1, w1f);

    if (ws_size >= NEED_A) {
        unsigned short* w2f = w1f + 32768;       // byte offset 65536
        unsigned short* nbf = w2f + 16384;       // byte offset 98304 (16B aligned)
        prep_w2<<<dim3(64), dim3(256), 0, stream>>>(W2, w2f);
        prep_node<<<dim3(25000), dim3(256), 0, stream>>>(node_emb, nbf);
        edge_mlp<true, false><<<dim3(8192), dim3(256), 0, stream>>>(
            node_emb, nbf, edge_index, edge_sel, W1, b1, W2, b2, w1f, w2f, out);
    } else if (ws_size >= NEED_B) {
        unsigned short* w2f = w1f + 32768;
        prep_w2<<<dim3(64), dim3(256), 0, stream>>>(W2, w2f);
        edge_mlp<false, false><<<dim3(8192), dim3(256), 0, stream>>>(
            node_emb, nullptr, edge_index, edge_sel, W1, b1, W2, b2, w1f, w2f, out);
    } else {
        edge_mlp<false, true><<<dim3(8192), dim3(256), 0, stream>>>(
            node_emb, nullptr, edge_index, edge_sel, W1, b1, W2, b2, w1f, nullptr, out);
    }
}